// Round 13
// baseline (2668.580 us; speedup 1.0000x reference)
//
#include <hip/hip_runtime.h>
#include <hip/hip_fp16.h>

typedef _Float16 f16;
typedef _Float16 f16x8 __attribute__((ext_vector_type(8)));
typedef float    f32x4 __attribute__((ext_vector_type(4)));
typedef unsigned int u32x4 __attribute__((ext_vector_type(4)));

#define HID 512
#define FEA 128
#define ROWSTR 129            // inputs row = 128 feat + 1 shock
#define SEQL 512
#define DEN1 64
#define NG 8                  // batch groups (16 rows each)
#define WPG 32                // workgroups per group
#define MB 16                 // batch rows per group
#define GC 16                 // gate columns per wg
#define THREADS 256

// workspace (bytes); zeroed every launch via hipMemsetAsync
#define WS_CTR    0                     // 64 u32: final-barrier counters
#define WS_HT     4096                  // 2*NG*MB*HID u32 tagged h = 524288 B
#define WS_SM     (WS_HT + 524288)      // 128 f32 shock means
#define WS_HPART  (WS_SM + 1024)        // NG*WPG*MB f32 head partials
#define WS_END    (WS_HPART + 16384)

#define WAITV0 { asm volatile("s_waitcnt vmcnt(0)" ::: "memory"); __builtin_amdgcn_sched_barrier(0); }

__device__ __forceinline__ void st_u32c(void* p, unsigned v) {
    asm volatile("global_store_dword %0, %1, off sc0 sc1" :: "v"(p), "v"(v) : "memory");
}
__device__ __forceinline__ unsigned ld_u32c(const void* p) {
    unsigned r;
    asm volatile("global_load_dword %0, %1, off sc0 sc1" : "=v"(r) : "v"(p) : "memory");
    asm volatile("s_waitcnt vmcnt(0)" ::: "memory");
    return r;
}
__device__ __forceinline__ void barrier_lgkm() {
    asm volatile("s_waitcnt lgkmcnt(0)" ::: "memory");
    __builtin_amdgcn_sched_barrier(0);
    __builtin_amdgcn_s_barrier();
    __builtin_amdgcn_sched_barrier(0);
    asm volatile("" ::: "memory");
}
// unpack 8 tagged u32 -> f16x8 (low halves)
__device__ __forceinline__ f16x8 unpack8(u32x4 a, u32x4 b) {
    union { unsigned u[4]; f16x8 v; } r;
    r.u[0] = (a[0] & 0xffffu) | (a[1] << 16);
    r.u[1] = (a[2] & 0xffffu) | (a[3] << 16);
    r.u[2] = (b[0] & 0xffffu) | (b[1] << 16);
    r.u[3] = (b[2] & 0xffffu) | (b[3] << 16);
    return r.v;
}
__device__ __forceinline__ unsigned tagbad(u32x4 a, unsigned wsh) {
    return ((a[0] ^ wsh) | (a[1] ^ wsh) | (a[2] ^ wsh) | (a[3] ^ wsh)) & 0xFFFF0000u;
}

__device__ __forceinline__ float sigmoid_f(float x) {
    x = fminf(fmaxf(x, -30.f), 30.f);
    return 1.f / (1.f + __expf(-x));
}
__device__ __forceinline__ float tanh_f(float x) {
    x = fminf(fmaxf(x, -15.f), 15.f);
    float e = __expf(2.f * x);
    return (e - 1.f) / (e + 1.f);
}

__global__ __launch_bounds__(THREADS)
void gru_fused(const float* __restrict__ inp, const float* __restrict__ Wk,
               const float* __restrict__ Rk,  const float* __restrict__ bias,
               const float* __restrict__ W1,  const float* __restrict__ b1,
               const float* __restrict__ gam, const float* __restrict__ bet,
               const float* __restrict__ mmn, const float* __restrict__ mvr,
               const float* __restrict__ W2,  const float* __restrict__ b2p,
               const float* __restrict__ Wsh, float* __restrict__ out,
               char* __restrict__ ws)
{
    __shared__ __align__(16) f16 Bh[512 * 48];   // 49152 B: R gate-col B-frags
    __shared__ __align__(16) f16 Bx[128 * 48];   // 12288 B: Wk gate-col B-frags
    __shared__ float red[4608];                   // 18432 B
    // LDS 79872 B -> 2 blocks/CU capacity (R1-R3/R11 proven regime)

    const int tid  = threadIdx.x;
    const int g    = blockIdx.x & (NG - 1);
    const int wgk  = blockIdx.x >> 3;
    const int lane = tid & 63;
    const int wave = tid >> 6;
    const int j0   = wgk * GC;

    unsigned* ctr   = (unsigned*)(ws + WS_CTR);
    unsigned* hT    = (unsigned*)(ws + WS_HT);     // tagged h: (tag<<16)|f16bits
    float*    smw   = (float*)(ws + WS_SM);
    float*    hpart = (float*)(ws + WS_HPART);

    // ---- stage B-fragments ----
    for (int idx = tid; idx < 512 * 48; idx += THREADS) {
        int kk = idx / 48, c = idx - kk * 48;
        int col = (c >> 4) * HID + j0 + (c & 15);
        Bh[((kk >> 3) * 48 + c) * 8 + (kk & 7)] = (f16)Rk[(size_t)kk * 1536 + col];
    }
    for (int idx = tid; idx < 128 * 48; idx += THREADS) {
        int kk = idx / 48, c = idx - kk * 48;
        int col = (c >> 4) * HID + j0 + (c & 15);
        Bx[((kk >> 3) * 48 + c) * 8 + (kk & 7)] = (f16)Wk[(size_t)kk * 1536 + col];
    }

    // ---- shock mean (coherent publish) ----
    if (wgk < MB) {
        int b = g * MB + wgk;
        float a = 0.f;
        for (int t = tid; t < SEQL; t += THREADS)
            a += inp[((size_t)b * SEQL + t) * ROWSTR + FEA];
        red[tid] = a;
        __syncthreads();
        for (int s = THREADS / 2; s > 0; s >>= 1) {
            if (tid < s) red[tid] += red[tid + s];
            __syncthreads();
        }
        if (tid == 0) {
            union { float f; unsigned u; } cv; cv.f = red[0] * (1.f / SEQL);
            st_u32c(smw + b, cv.u);
        }
    }

    // per-thread constants
    const int brow  = tid >> 4;
    const int jcol  = j0 + (tid & 15);
    const int arow  = lane & 15;
    const int ahalf = lane >> 4;
    const int lcol  = j0 + (lane & 15);
    const float bZ3  = bias[lcol] + bias[1536 + lcol];
    const float bR3  = bias[512 + lcol] + bias[1536 + 512 + lcol];
    const float bX3  = bias[1024 + lcol];
    const float bHH3 = bias[1536 + 1024 + lcol];

    float xa[4][8];   // wave3: x floats, ~2 steps ahead
    u32x4 ta[10];     // speculative tagged h loads (waves<3 use 10, wave3 uses 2)

    // issue this wave's tagged h-loads for ring slot `slot` (speculative-safe)
    auto issue_h = [&](int slot) {
        const unsigned* hb = hT + ((size_t)slot * NG + g) * MB * HID
                                + (size_t)arow * HID
                                + (wave < 3 ? wave * 5 * 32 : 15 * 32) + ahalf * 8;
        if (wave < 3) {
            #pragma unroll
            for (int s = 0; s < 5; ++s) {
                asm volatile("global_load_dwordx4 %0, %1, off offset:%c2 sc0 sc1"
                             : "=v"(ta[2*s])   : "v"(hb), "i"(s * 128));
                asm volatile("global_load_dwordx4 %0, %1, off offset:%c2 sc0 sc1"
                             : "=v"(ta[2*s+1]) : "v"(hb), "i"(s * 128 + 16));
            }
        } else {
            asm volatile("global_load_dwordx4 %0, %1, off sc0 sc1"           : "=v"(ta[0]) : "v"(hb));
            asm volatile("global_load_dwordx4 %0, %1, off offset:16 sc0 sc1" : "=v"(ta[1]) : "v"(hb));
        }
    };
    auto check_bad = [&](unsigned wsh) -> unsigned {
        unsigned bad = 0;
        if (wave < 3) {
            #pragma unroll
            for (int j = 0; j < 10; ++j) bad |= tagbad(ta[j], wsh);
        } else {
            bad = tagbad(ta[0], wsh) | tagbad(ta[1], wsh);
        }
        return bad;
    };

    auto x_window = [&](int t) {   // convert x(t+1), 12 MFMAs, stash, load x(t+2)
        f16x8 afx[4];
        #pragma unroll
        for (int s = 0; s < 4; ++s) {
            f16x8 a;
            #pragma unroll
            for (int q = 0; q < 8; ++q) a[q] = (f16)xa[s][q];
            afx[s] = a;
        }
        f32x4 az = {0,0,0,0}, ar = {0,0,0,0}, ah = {0,0,0,0};
        #pragma unroll
        for (int s = 0; s < 4; ++s) {
            const f16x8* bx = ((const f16x8*)Bx) + (s * 4 + ahalf) * 48 + (lane & 15);
            az = __builtin_amdgcn_mfma_f32_16x16x32_f16(afx[s], bx[0],  az, 0, 0, 0);
            ar = __builtin_amdgcn_mfma_f32_16x16x32_f16(afx[s], bx[16], ar, 0, 0, 0);
            ah = __builtin_amdgcn_mfma_f32_16x16x32_f16(afx[s], bx[32], ah, 0, 0, 0);
        }
        float* xo = red + 3072 + ((t + 1) & 1) * 768;
        #pragma unroll
        for (int i = 0; i < 4; ++i) {
            int rix = (ahalf * 4 + i) * 16 + (lane & 15);
            xo[rix]       = az[i] + bZ3;
            xo[256 + rix] = ar[i] + bR3;
            xo[512 + rix] = ah[i] + bX3;
        }
        int tt = (t + 2 < SEQL) ? t + 2 : SEQL - 1;
        const float* xs = inp + ((size_t)(g * MB + arow) * SEQL + tt) * ROWSTR + ahalf * 8;
        #pragma unroll
        for (int s = 0; s < 4; ++s)
            #pragma unroll
            for (int q = 0; q < 8; ++q)
                xa[s][q] = xs[s * 32 + q];
    };

    __syncthreads();   // staging + shock-mean done

    if (wave == 3) {   // prologue: stash x-proj(0), issue x(1)
        const float* xs = inp + ((size_t)(g * MB + arow) * SEQL + 0) * ROWSTR + ahalf * 8;
        #pragma unroll
        for (int s = 0; s < 4; ++s)
            #pragma unroll
            for (int q = 0; q < 8; ++q)
                xa[s][q] = xs[s * 32 + q];
        x_window(-1);
    }
    issue_h(0);        // speculative issue for t=0 (tags memset 0 == want)

    float hold = 0.f;  // own h element (h0 = 0)

    #pragma unroll 1
    for (int t = 0; t < SEQL; ++t) {
        const int cur = t & 1;
        const unsigned wsh = (unsigned)t << 16;

        // ---- check speculative loads; retry only if producers were late ----
        WAITV0;
        {
            unsigned bad = check_bad(wsh);
            while (!__all((int)(bad == 0))) {
                issue_h(cur);
                WAITV0;
                bad = check_bad(wsh);
            }
        }
        f16x8 af[5];
        if (wave < 3) {
            #pragma unroll
            for (int s = 0; s < 5; ++s) af[s] = unpack8(ta[2*s], ta[2*s+1]);
        } else {
            af[0] = unpack8(ta[0], ta[1]);
        }

        // ---- MFMA partials (R3 structure) ----
        f32x4 aZ = {0,0,0,0}, aR = {0,0,0,0}, aH = {0,0,0,0};
        if (wave < 3) {
            #pragma unroll
            for (int s = 0; s < 5; ++s) {
                int ks = wave * 5 + s;
                const f16x8* bp = ((const f16x8*)Bh) + (ks * 4 + ahalf) * 48 + (lane & 15);
                aZ = __builtin_amdgcn_mfma_f32_16x16x32_f16(af[s], bp[0],  aZ, 0, 0, 0);
                aR = __builtin_amdgcn_mfma_f32_16x16x32_f16(af[s], bp[16], aR, 0, 0, 0);
                aH = __builtin_amdgcn_mfma_f32_16x16x32_f16(af[s], bp[32], aH, 0, 0, 0);
            }
            #pragma unroll
            for (int i = 0; i < 4; ++i) {
                int rix = (ahalf * 4 + i) * 16 + (lane & 15);
                red[wave * 768 +       rix] = aZ[i];
                red[wave * 768 + 256 + rix] = aR[i];
                red[wave * 768 + 512 + rix] = aH[i];
            }
        } else {
            const f16x8* bp = ((const f16x8*)Bh) + (15 * 4 + ahalf) * 48 + (lane & 15);
            aZ = __builtin_amdgcn_mfma_f32_16x16x32_f16(af[0], bp[0],  aZ, 0, 0, 0);
            aR = __builtin_amdgcn_mfma_f32_16x16x32_f16(af[0], bp[16], aR, 0, 0, 0);
            aH = __builtin_amdgcn_mfma_f32_16x16x32_f16(af[0], bp[32], aH, 0, 0, 0);
            #pragma unroll
            for (int i = 0; i < 4; ++i) {
                int rix = (ahalf * 4 + i) * 16 + (lane & 15);
                red[3 * 768 +       rix] = aZ[i];
                red[3 * 768 + 256 + rix] = aR[i];
                red[3 * 768 + 512 + rix] = aH[i] + bHH3;
            }
        }
        barrier_lgkm();   // partials + x-stash visible

        // ---- gates: thread owns (brow, jcol); tagged store, NO drain, NO flag ----
        {
            float zp = red[tid] + red[768 + tid] + red[1536 + tid] + red[2304 + tid];
            float rp = red[256 + tid] + red[1024 + tid] + red[1792 + tid] + red[2560 + tid];
            float hp = red[512 + tid] + red[1280 + tid] + red[2048 + tid] + red[2816 + tid];
            const float* xi = red + 3072 + cur * 768;
            float z = sigmoid_f(zp + xi[tid]);
            float r = sigmoid_f(rp + xi[256 + tid]);
            float hc = tanh_f(xi[512 + tid] + r * hp);
            float hnew = z * hold + (1.f - z) * hc;
            f16 h16 = (f16)hnew;
            hold = (float)h16;
            union { f16 h; unsigned short u; } cv; cv.h = h16;
            st_u32c(hT + ((size_t)(cur ^ 1) * NG + g) * MB * HID
                       + (size_t)brow * HID + jcol,
                    (unsigned)cv.u | ((unsigned)(t + 1) << 16));
        }

        // ---- speculative issue for step t+1: RTT hides under x_window + barriers ----
        if (t + 1 < SEQL) issue_h(cur ^ 1);

        if (wave == 3 && t + 1 < SEQL)
            x_window(t);     // x(t+2) loads in flight; next check's WAITV0 drains all

        barrier_lgkm();      // red/x-stash reuse safe
    }

    __syncthreads();

    // ---- head: tagged poll-read of h_512 (slot 0, tag == SEQL) ----
    const unsigned* hf = hT + ((size_t)g * MB + brow) * HID + (tid & 15) * 32;
    const int c0 = wgk * 2;
    u32x4 hv[8];
    for (;;) {
        #pragma unroll
        for (int c8 = 0; c8 < 8; ++c8)
            asm volatile("global_load_dwordx4 %0, %1, off offset:%c2 sc0 sc1"
                         : "=v"(hv[c8]) : "v"(hf), "i"(c8 * 16));
        WAITV0;
        unsigned bad = 0;
        #pragma unroll
        for (int c8 = 0; c8 < 8; ++c8) bad |= tagbad(hv[c8], (unsigned)SEQL << 16);
        if (__all((int)(bad == 0))) break;
    }
    float p0 = 0.f, p1 = 0.f, w0 = 0.f, w1 = 0.f;
    for (int c8 = 0; c8 < 8; ++c8) {
        #pragma unroll
        for (int e = 0; e < 4; ++e) {
            int k = (tid & 15) * 32 + c8 * 4 + e;
            union { unsigned short s; f16 h; } cc;
            cc.s = (unsigned short)(hv[c8][e] & 0xffffu);
            float hvv = (float)cc.h;
            float a0 = W1[(size_t)k * DEN1 + c0];
            float a1 = W1[(size_t)k * DEN1 + c0 + 1];
            p0 += hvv * a0; p1 += hvv * a1; w0 += a0; w1 += a1;
        }
    }
    __syncthreads();
    red[tid] = p0; red[256 + tid] = w0; red[512 + tid] = p1; red[768 + tid] = w1;
    __syncthreads();
    if (tid < 32) {
        int b = tid >> 1, cc = tid & 1;
        int c = c0 + cc;
        float dot = 0.f, wsum = 0.f;
        for (int i = 0; i < 16; ++i) {
            dot  += red[cc * 512 + b * 16 + i];
            wsum += red[cc * 512 + 256 + b * 16 + i];
        }
        union { unsigned u; float f; } sm; sm.u = ld_u32c(smw + g * MB + b);
        float sW = sm.f * Wsh[0];
        float d = dot + sW * wsum + b1[c];
        d = fmaxf(d, 0.f);
        d = (d - mmn[c]) * rsqrtf(mvr[c] + 0.001f) * gam[c] + bet[c];
        red[1024 + tid] = d * W2[c];
    }
    __syncthreads();
    if (tid < MB)
        hpart[((size_t)g * WPG + wgk) * MB + tid] = red[1024 + tid * 2] + red[1024 + tid * 2 + 1];
    __syncthreads();
    if (tid == 0) {
        __builtin_amdgcn_fence(__ATOMIC_RELEASE, "agent");
        unsigned* c9 = ctr + g;
        unsigned old = __hip_atomic_fetch_add(c9, 1u, __ATOMIC_RELAXED, __HIP_MEMORY_SCOPE_AGENT);
        if (old != WPG - 1)
            while (__hip_atomic_load(c9, __ATOMIC_RELAXED, __HIP_MEMORY_SCOPE_AGENT) < WPG) {}
        __builtin_amdgcn_fence(__ATOMIC_ACQUIRE, "agent");
    }
    __syncthreads();
    if (wgk == 0 && tid < MB) {
        float o = b2p[0];
        for (int k = 0; k < WPG; ++k)
            o += hpart[((size_t)g * WPG + k) * MB + tid];
        out[g * MB + tid] = o;
    }
}

extern "C" void kernel_launch(void* const* d_in, const int* in_sizes, int n_in,
                              void* d_out, int out_size, void* d_ws, size_t ws_size,
                              hipStream_t stream) {
    (void)in_sizes; (void)n_in; (void)out_size; (void)ws_size;
    const float* inp  = (const float*)d_in[0];
    const float* Wk   = (const float*)d_in[1];
    const float* Rk   = (const float*)d_in[2];
    const float* bias = (const float*)d_in[3];
    const float* W1   = (const float*)d_in[4];
    const float* b1   = (const float*)d_in[5];
    const float* gam  = (const float*)d_in[6];
    const float* bet  = (const float*)d_in[7];
    const float* mmn  = (const float*)d_in[8];
    const float* mvr  = (const float*)d_in[9];
    const float* W2   = (const float*)d_in[10];
    const float* b2p  = (const float*)d_in[11];
    const float* Wsh  = (const float*)d_in[12];

    hipMemsetAsync(d_ws, 0, WS_END, stream);   // tags=0 (== want at t=0), h0=0, ctr=0
    hipLaunchKernelGGL(gru_fused, dim3(NG * WPG), dim3(THREADS), 0, stream,
                       inp, Wk, Rk, bias, W1, b1, gam, bet, mmn, mvr, W2, b2p, Wsh,
                       (float*)d_out, (char*)d_ws);
}

// Round 14
// 1384.588 us; speedup vs baseline: 1.9273x; 1.9273x over previous
//
#include <hip/hip_runtime.h>
#include <hip/hip_fp16.h>

typedef _Float16 f16;
typedef _Float16 f16x8 __attribute__((ext_vector_type(8)));
typedef float    f32x4 __attribute__((ext_vector_type(4)));

#define HID 512
#define FEA 128
#define ROWSTR 129            // inputs row = 128 feat + 1 shock
#define SEQL 512
#define DEN1 64
#define NG 8                  // batch groups (16 rows each)
#define WPG 32                // workgroups per group
#define MB 16                 // batch rows per group
#define GC 16                 // gate columns per wg
#define THREADS 256
#define KTOT 640              // 512 (h via R) + 128 (x via kernel)

// workspace layout (bytes); zeroed every launch via hipMemsetAsync
#define WS_CTR    0                     // NG u32 final-barrier counters
#define WS_FLG    256                   // NG*32 u32 step flags (128B per group)
#define WS_HRING  4096                  // 2*NG*MB*HID f16 = 262144 B
#define WS_SM     (WS_HRING + 262144)   // 128 f32 shock means
#define WS_HPART  (WS_SM + 1024)        // NG*WPG*MB f32 head partials
#define WS_END    (WS_HPART + 16384)

#define AT_LD(p)  __hip_atomic_load((p),  __ATOMIC_RELAXED, __HIP_MEMORY_SCOPE_AGENT)

union H4 { unsigned long long u; f16 h[4]; };

// --- device-coherent (bypass L1+L2) asm memory ops; batched, no implicit waits ---
__device__ __forceinline__ f16x8 ld_h16(const f16* p) {
    f16x8 r;
    asm volatile("global_load_dwordx4 %0, %1, off sc0 sc1" : "=v"(r) : "v"(p));
    return r;
}
__device__ __forceinline__ void st_h64(void* p, unsigned long long v) {
    asm volatile("global_store_dwordx2 %0, %1, off sc0 sc1" :: "v"(p), "v"(v) : "memory");
}
__device__ __forceinline__ unsigned ld_flag(const unsigned* p) {
    unsigned r;
    asm volatile("global_load_dword %0, %1, off sc0 sc1" : "=v"(r) : "v"(p) : "memory");
    asm volatile("s_waitcnt vmcnt(0)" ::: "memory");
    return r;
}
__device__ __forceinline__ void st_flag(unsigned* p, unsigned v) {
    asm volatile("global_store_dword %0, %1, off sc0 sc1" :: "v"(p), "v"(v) : "memory");
}
__device__ __forceinline__ void wait_vm0() {
    asm volatile("s_waitcnt vmcnt(0)" ::: "memory");
    __builtin_amdgcn_sched_barrier(0);
}

__device__ __forceinline__ float sigmoid_f(float x) {
    x = fminf(fmaxf(x, -30.f), 30.f);
    return 1.f / (1.f + __expf(-x));
}
__device__ __forceinline__ float tanh_f(float x) {
    x = fminf(fmaxf(x, -15.f), 15.f);
    float e = __expf(2.f * x);
    return (e - 1.f) / (e + 1.f);
}

__global__ __launch_bounds__(THREADS)
void gru_fused(const float* __restrict__ inp, const float* __restrict__ Wk,
               const float* __restrict__ Rk,  const float* __restrict__ bias,
               const float* __restrict__ W1,  const float* __restrict__ b1,
               const float* __restrict__ gam, const float* __restrict__ bet,
               const float* __restrict__ mmn, const float* __restrict__ mvr,
               const float* __restrict__ W2,  const float* __restrict__ b2p,
               const float* __restrict__ Wsh, float* __restrict__ out,
               char* __restrict__ ws)
{
    __shared__ __align__(16) f16 Bl[KTOT * 48];   // 61440 B: [R;Wk] slice as B-fragments
    __shared__ float red[4096];                    // 16384 B: reductions
    __shared__ __align__(8) f16 htile[256];        // this wg's 16x16 h-output tile

    const int tid  = threadIdx.x;
    const int g    = blockIdx.x & (NG - 1);   // group; bid%8 -> likely XCD-local
    const int wgk  = blockIdx.x >> 3;         // rank within group, 0..31
    const int lane = tid & 63;
    const int wave = tid >> 6;
    const int j0   = wgk * GC;                // first gate column owned

    unsigned* ctr   = (unsigned*)(ws + WS_CTR);
    unsigned* flg   = (unsigned*)(ws + WS_FLG);
    f16*      hring = (f16*)(ws + WS_HRING);
    float*    smw   = (float*)(ws + WS_SM);
    float*    hpart = (float*)(ws + WS_HPART);

    // ---- stage B = [R; Wk] gate-col slice (48 cols: z,r,h) into LDS as f16 frags ----
    for (int idx = tid; idx < KTOT * 48; idx += THREADS) {
        int kk  = idx / 48;
        int c   = idx - kk * 48;
        int col = (c >> 4) * HID + j0 + (c & 15);
        float v = (kk < HID) ? Rk[(size_t)kk * 1536 + col]
                             : Wk[(size_t)(kk - HID) * 1536 + col];
        Bl[((size_t)(kk >> 3) * 48 + c) * 8 + (kk & 7)] = (f16)v;
    }

    // ---- shock mean: wg with wgk<16 computes batch row g*16+wgk ----
    if (wgk < MB) {
        int b = g * MB + wgk;
        float a = 0.f;
        for (int t = tid; t < SEQL; t += THREADS)
            a += inp[((size_t)b * SEQL + t) * ROWSTR + FEA];
        red[tid] = a;
        __syncthreads();
        for (int s = THREADS / 2; s > 0; s >>= 1) {
            if (tid < s) red[tid] += red[tid + s];
            __syncthreads();
        }
        if (tid == 0) smw[b] = red[0] * (1.f / SEQL);
    }

    // per-thread gate constants; thread -> (brow=tid>>4, col=tid&15)
    const int brow = tid >> 4;
    const int jcol = j0 + (tid & 15);
    const float bZ  = bias[jcol]           + bias[1536 + jcol];
    const float bR  = bias[512 + jcol]     + bias[1536 + 512 + jcol];
    const float bXH = bias[1024 + jcol];                   // input bias, cand
    const float bHH = bias[1536 + 1024 + jcol];            // recurrent bias, cand

    const int arow  = lane & 15;    // A-frag row (batch row within block)
    const int ahalf = lane >> 4;    // A-frag k-subchunk

    float xa[4][8];                 // wave 3: prefetched x floats for current step
    if (wave == 3) {
        const float* xb = inp + ((size_t)(g * MB + arow) * SEQL + 0) * ROWSTR + ahalf * 8;
        #pragma unroll
        for (int s = 0; s < 4; ++s)
            #pragma unroll
            for (int q = 0; q < 8; ++q)
                xa[s][q] = xb[s * 32 + q];
    }

    float hold = 0.f;               // this thread's own h element (h0 = 0)
    __syncthreads();                // Bl ready

    for (int t = 0; t < SEQL; ++t) {
        const int cur = t & 1;
        const f16* hb = hring + ((size_t)cur * NG + g) * MB * HID
                              + (size_t)arow * HID + ahalf * 8;

        f32x4 aZ = {0,0,0,0}, aR = {0,0,0,0}, aH = {0,0,0,0}, aX = {0,0,0,0};

        if (wave < 3) {             // k-steps 5w..5w+4, all from h
            f16x8 af[5];
            #pragma unroll
            for (int s = 0; s < 5; ++s)
                af[s] = ld_h16(hb + (wave * 5 + s) * 32);   // batched coherent loads
            wait_vm0();                                      // ONE drain for all 5
            #pragma unroll
            for (int s = 0; s < 5; ++s) {
                int ks = wave * 5 + s;
                const f16x8* bp = ((const f16x8*)Bl) + (ks * 4 + ahalf) * 48 + (lane & 15);
                f16x8 bz = bp[0], br = bp[16], bh = bp[32];
                aZ = __builtin_amdgcn_mfma_f32_16x16x32_f16(af[s], bz, aZ, 0, 0, 0);
                aR = __builtin_amdgcn_mfma_f32_16x16x32_f16(af[s], br, aR, 0, 0, 0);
                aH = __builtin_amdgcn_mfma_f32_16x16x32_f16(af[s], bh, aH, 0, 0, 0);
            }
        } else {                    // wave 3: k-step 15 from h, 16..19 from x
            f16x8 af0 = ld_h16(hb + 15 * 32);
            f16x8 afx[4];
            #pragma unroll
            for (int s = 0; s < 4; ++s) {
                f16x8 a;
                #pragma unroll
                for (int q = 0; q < 8; ++q) a[q] = (f16)xa[s][q];
                afx[s] = a;
            }
            wait_vm0();             // af0 ready (x prefetch for t+1 happens later)
            {
                const f16x8* bp = ((const f16x8*)Bl) + (15 * 4 + ahalf) * 48 + (lane & 15);
                aZ = __builtin_amdgcn_mfma_f32_16x16x32_f16(af0, bp[0],  aZ, 0, 0, 0);
                aR = __builtin_amdgcn_mfma_f32_16x16x32_f16(af0, bp[16], aR, 0, 0, 0);
                aH = __builtin_amdgcn_mfma_f32_16x16x32_f16(af0, bp[32], aH, 0, 0, 0);
            }
            #pragma unroll
            for (int s = 0; s < 4; ++s) {
                int ks = 16 + s;
                const f16x8* bp = ((const f16x8*)Bl) + (ks * 4 + ahalf) * 48 + (lane & 15);
                aZ = __builtin_amdgcn_mfma_f32_16x16x32_f16(afx[s], bp[0],  aZ, 0, 0, 0);
                aR = __builtin_amdgcn_mfma_f32_16x16x32_f16(afx[s], bp[16], aR, 0, 0, 0);
                aX = __builtin_amdgcn_mfma_f32_16x16x32_f16(afx[s], bp[32], aX, 0, 0, 0);
            }
        }

        // stash K-split partials: D layout col=lane&15, row=(lane>>4)*4+i
        #pragma unroll
        for (int i = 0; i < 4; ++i) {
            int ridx = (ahalf * 4 + i) * 16 + (lane & 15);
            red[wave * 1024 +       ridx] = aZ[i];
            red[wave * 1024 + 256 + ridx] = aR[i];
            red[wave * 1024 + 512 + ridx] = aH[i];
        }
        if (wave == 3) {
            #pragma unroll
            for (int i = 0; i < 4; ++i) {
                int ridx = (ahalf * 4 + i) * 16 + (lane & 15);
                red[3 * 1024 + 768 + ridx] = aX[i];
            }
            {   // prefetch next step's x (plain cached loads; drained by next wait_vm0)
                int tt = (t + 1 < SEQL) ? t + 1 : SEQL - 1;
                const float* xb = inp + ((size_t)(g * MB + arow) * SEQL + tt) * ROWSTR + ahalf * 8;
                #pragma unroll
                for (int s = 0; s < 4; ++s)
                    #pragma unroll
                    for (int q = 0; q < 8; ++q)
                        xa[s][q] = xb[s * 32 + q];
            }
        }
        __syncthreads();

        // reduce + gates; thread owns element (brow, jcol); ridx identity == tid
        float zp = red[tid] + red[1024 + tid] + red[2048 + tid] + red[3072 + tid];
        float rp = red[256 + tid] + red[1280 + tid] + red[2304 + tid] + red[3328 + tid];
        float hp = red[512 + tid] + red[1536 + tid] + red[2560 + tid] + red[3584 + tid];
        float xp = red[3840 + tid];

        float z = sigmoid_f(zp + bZ);
        float r = sigmoid_f(rp + bR);
        float hcand = tanh_f((xp + bXH) + r * (hp + bHH));
        float hnew = z * hold + (1.f - z) * hcand;
        f16 h16 = (f16)hnew;
        hold = (float)h16;
        htile[brow * 16 + (tid & 15)] = h16;   // gather for wide coherent stores
        __syncthreads();

        // wave 0: publish tile (64 x 8B coherent stores), drain, flag, poll
        if (tid < 64) {
            int row = tid >> 2, q = tid & 3;
            unsigned long long val = *(const unsigned long long*)(htile + row * 16 + q * 4);
            st_h64(hring + (((size_t)(cur ^ 1) * NG + g) * MB + row) * HID + j0 + q * 4, val);
        }
        if (wave == 0) {
            asm volatile("s_waitcnt vmcnt(0)" ::: "memory");   // h-stores at coherence point
            if (lane == 0) st_flag(flg + g * 32 + wgk, (unsigned)(t + 1));
            const unsigned want = (unsigned)(t + 1);
            for (;;) {
                unsigned v = ld_flag(flg + g * 32 + (lane & 31));
                if (__all((int)(v >= want))) break;
            }
        }
        __syncthreads();
    }

    // ---- head: state=(h + shock_mean*W_shock); relu(state@W1+b1); BN; @W2+b2 ----
    // final h is in ring slot 0 (t=511 wrote cur^1 = 0); read via coherent loads
    const unsigned long long* hfq = (const unsigned long long*)
        (hring + ((size_t)g * MB + brow) * HID);
    const int sub = tid & 15;
    const int c0 = wgk * 2;          // this wg's two DENSE1 columns
    float p0 = 0.f, p1 = 0.f, w0 = 0.f, w1 = 0.f;
    for (int c8 = 0; c8 < 8; ++c8) {
        H4 x; x.u = AT_LD(hfq + sub * 8 + c8);
        #pragma unroll
        for (int e = 0; e < 4; ++e) {
            int k = sub * 32 + c8 * 4 + e;
            float hv = (float)x.h[e];
            float a0 = W1[(size_t)k * DEN1 + c0];
            float a1 = W1[(size_t)k * DEN1 + c0 + 1];
            p0 += hv * a0; p1 += hv * a1; w0 += a0; w1 += a1;
        }
    }
    red[tid] = p0; red[256 + tid] = w0; red[512 + tid] = p1; red[768 + tid] = w1;
    __syncthreads();
    if (tid < 32) {
        int b = tid >> 1, cc = tid & 1;
        int c = c0 + cc;
        float dot = 0.f, wsum = 0.f;
        for (int i = 0; i < 16; ++i) {
            dot  += red[cc * 512 + b * 16 + i];
            wsum += red[cc * 512 + 256 + b * 16 + i];
        }
        float sW = smw[g * MB + b] * Wsh[0];
        float d = dot + sW * wsum + b1[c];
        d = fmaxf(d, 0.f);
        d = (d - mmn[c]) * rsqrtf(mvr[c] + 0.001f) * gam[c] + bet[c];
        red[1024 + tid] = d * W2[c];
    }
    __syncthreads();
    if (tid < MB)
        hpart[((size_t)g * WPG + wgk) * MB + tid] = red[1024 + tid * 2] + red[1024 + tid * 2 + 1];
    __syncthreads();
    // final heavy barrier (once): full fences so plain loads of smw/hpart are fresh
    if (tid == 0) {
        __builtin_amdgcn_fence(__ATOMIC_RELEASE, "agent");
        unsigned* c9 = ctr + g;
        unsigned old = __hip_atomic_fetch_add(c9, 1u, __ATOMIC_RELAXED, __HIP_MEMORY_SCOPE_AGENT);
        if (old != WPG - 1)
            while (AT_LD(c9) < WPG) {}
        __builtin_amdgcn_fence(__ATOMIC_ACQUIRE, "agent");
    }
    __syncthreads();
    if (wgk == 0 && tid < MB) {
        float o = b2p[0];
        for (int k = 0; k < WPG; ++k)       // fixed order -> deterministic
            o += hpart[((size_t)g * WPG + k) * MB + tid];
        out[g * MB + tid] = o;
    }
}

extern "C" void kernel_launch(void* const* d_in, const int* in_sizes, int n_in,
                              void* d_out, int out_size, void* d_ws, size_t ws_size,
                              hipStream_t stream) {
    (void)in_sizes; (void)n_in; (void)out_size; (void)ws_size;
    const float* inp  = (const float*)d_in[0];
    const float* Wk   = (const float*)d_in[1];
    const float* Rk   = (const float*)d_in[2];
    const float* bias = (const float*)d_in[3];
    const float* W1   = (const float*)d_in[4];
    const float* b1   = (const float*)d_in[5];
    const float* gam  = (const float*)d_in[6];
    const float* bet  = (const float*)d_in[7];
    const float* mmn  = (const float*)d_in[8];
    const float* mvr  = (const float*)d_in[9];
    const float* W2   = (const float*)d_in[10];
    const float* b2p  = (const float*)d_in[11];
    const float* Wsh  = (const float*)d_in[12];

    hipMemsetAsync(d_ws, 0, WS_END, stream);   // flags/counters + h0 = 0, every launch
    hipLaunchKernelGGL(gru_fused, dim3(NG * WPG), dim3(THREADS), 0, stream,
                       inp, Wk, Rk, bias, W1, b1, gam, bet, mmn, mvr, W2, b2p, Wsh,
                       (float*)d_out, (char*)d_ws);
}